// Round 1
// baseline (185.347 us; speedup 1.0000x reference)
//
#include <hip/hip_runtime.h>
#include <math.h>

#define N_PTS 2048
#define N_SETS 16          // B*S = 2*8
#define B_VAL 2.0f
#define BLOCK 256
#define SEGS 16
#define CPS (N_PTS / SEGS)   // 128 candidates per segment
#define QPT 8                // queries per thread (2048 / 256)
#define NGRP (N_SETS * 2)    // 32 (set,dir) groups

// ws layout:
//   [0 .. 8MB)      float2 partials: [(group*SEGS + seg) * 2048 + q]
//   [8MB .. +644B)  control words (uint32/float32):
//     [0..31]   per-group arrival counters   (zeroed by memset)
//     [32]      global merge counter         (zeroed by memset)
//     [33..64]  loss_part[32]                (unconditionally written)
//     [65..160] csum[32][3] coordinate sums  (unconditionally written)
#define CTRL_OFF ((size_t)NGRP * SEGS * N_PTS * sizeof(float2))   // 8 MB

__device__ __forceinline__ float sl1(float d) {
    d = fabsf(d);
    return d < 1.0f ? 0.5f * d * d : d - 0.5f;
}

// grid = (SEGS, N_SETS, 2). Fused single kernel:
//  phase 1: per-segment argmin partials (identical math to the proven R5 kernel;
//           SEGS=16 measured-optimal, packed-fp32 regressed (R4), SEGS=32 regressed (R5)).
//  phase 2 (last block of each group, via device-scope counter): merge 16 segs,
//           smooth-L1 using register-held query coords, store weighted partial.
//  phase 3 (last merge block of 32): assemble out[0]/out[1] with plain stores.
__global__ __launch_bounds__(BLOCK) void chamfer_fused(
    const float* __restrict__ X, const float* __restrict__ T,
    const float* __restrict__ W, float2* __restrict__ ws,
    float* __restrict__ out)
{
    const int seg = blockIdx.x;
    const int set = blockIdx.y;
    const int dir = blockIdx.z;
    const int tid = threadIdx.x;
    const int g   = set * 2 + dir;

    unsigned int* ctrl = (unsigned int*)((char*)ws + CTRL_OFF);
    float* ctrlf = (float*)ctrl;

    const float* psrc = (dir == 0) ? (X + (size_t)set * N_PTS * 3)
                                   : (T + (size_t)set * N_PTS * 3);
    const float* csrc = (dir == 0) ? (T + (size_t)set * N_PTS * 3)
                                   : (X + (size_t)set * N_PTS * 3);

    // Stage this segment's candidates as (x,y,z,|c|^2) float4 in LDS.
    __shared__ float4 cand[CPS];
    if (tid < CPS) {
        const int gidx = seg * CPS + tid;
        float cx = csrc[gidx * 3 + 0];
        float cy = csrc[gidx * 3 + 1];
        float cz = csrc[gidx * 3 + 2];
        cand[tid] = make_float4(cx, cy, cz, cx * cx + cy * cy + cz * cz);
    }
    __syncthreads();

    // My 8 query points; precompute -2*coord (|p|^2 dropped: constant
    // shift per query, argmin-invariant).
    float ax[QPT], ay[QPT], az[QPT];
    float best[QPT];
    int   bidx[QPT];
#pragma unroll
    for (int j = 0; j < QPT; ++j) {
        const int q = tid + BLOCK * j;
        ax[j] = -2.0f * psrc[q * 3 + 0];
        ay[j] = -2.0f * psrc[q * 3 + 1];
        az[j] = -2.0f * psrc[q * 3 + 2];
        best[j] = INFINITY;
        bidx[j] = 0;
    }

    // One broadcast LDS read amortized over 8 queries (48 VALU / ds_read).
    // Strict <: first occurrence wins (ascending m) == jnp.argmin tiebreak.
    // Floor: 6 VALU/pair (3 fma + cmp + 2 cndmask) -> ~10 us GPU-wide.
#pragma unroll 4
    for (int m = 0; m < CPS; ++m) {
        float4 c = cand[m];
#pragma unroll
        for (int j = 0; j < QPT; ++j) {
            float d = fmaf(ax[j], c.x, fmaf(ay[j], c.y, fmaf(az[j], c.z, c.w)));
            if (d < best[j]) { best[j] = d; bidx[j] = m; }
        }
    }

    // Contention-free coalesced stores: ws[(g*SEGS+seg)*2048 + q].
    float2* wq = ws + ((size_t)(g * SEGS + seg) << 11);
#pragma unroll
    for (int j = 0; j < QPT; ++j) {
        const int q = tid + BLOCK * j;
        float2 v;
        v.x = best[j];
        v.y = __uint_as_float((unsigned int)(seg * CPS + bidx[j]));
        wq[q] = v;
    }

    // seg-0 blocks also produce this direction's coordinate sums (they read
    // all 2048 source points anyway). ax = -2x is exact; *(-0.5) is exact,
    // so the accumulation matches the previous centroid path bit-for-bit.
    __shared__ float red[4][3];
    if (seg == 0) {
        float s0 = 0.f, s1 = 0.f, s2 = 0.f;
#pragma unroll
        for (int j = 0; j < QPT; ++j) { s0 += ax[j]; s1 += ay[j]; s2 += az[j]; }
        for (int off = 32; off > 0; off >>= 1) {
            s0 += __shfl_down(s0, off, 64);
            s1 += __shfl_down(s1, off, 64);
            s2 += __shfl_down(s2, off, 64);
        }
        if ((tid & 63) == 0) {
            red[tid >> 6][0] = s0; red[tid >> 6][1] = s1; red[tid >> 6][2] = s2;
        }
        __syncthreads();
        if (tid == 0) {
#pragma unroll
            for (int k = 0; k < 3; ++k)
                ctrlf[65 + g * 3 + k] =
                    -0.5f * (red[0][k] + red[1][k] + red[2][k] + red[3][k]);
        }
    }

    // ---- arrival: canonical threadfence-reduction pattern ----
    __threadfence();          // make this thread's global stores device-visible
    __syncthreads();          // all threads' fences precede tid0's atomic
    __shared__ int slast;
    if (tid == 0) {
        unsigned int t = atomicAdd(&ctrl[g], 1u);
        slast = (t == SEGS - 1);
    }
    __syncthreads();
    if (!slast) return;

    // ---- phase 2: merge for this (set,dir) group (one block) ----
    __threadfence();          // acquire: other blocks' partials
    const float2* wp = ws + ((size_t)(g * SEGS) << 11);
    float lsum = 0.0f;
#pragma unroll
    for (int j = 0; j < QPT; ++j) {
        const int q = tid + BLOCK * j;
        float bd = INFINITY;
        unsigned int idx = 0;
        // Ascending seg + strict < == lowest-index tiebreak (matches jnp.argmin).
#pragma unroll
        for (int s = 0; s < SEGS; ++s) {
            float2 v = wp[((size_t)s << 11) + q];
            if (v.x < bd) { bd = v.x; idx = __float_as_uint(v.y); }
        }
        // Query coords recovered exactly from registers: -0.5 * (-2x) == x.
        const float px = -0.5f * ax[j], py = -0.5f * ay[j], pz = -0.5f * az[j];
        lsum += sl1(px - csrc[idx * 3 + 0])
              + sl1(py - csrc[idx * 3 + 1])
              + sl1(pz - csrc[idx * 3 + 2]);
    }
    __shared__ float red2[4];
    for (int off = 32; off > 0; off >>= 1)
        lsum += __shfl_down(lsum, off, 64);
    if ((tid & 63) == 0) red2[tid >> 6] = lsum;
    __syncthreads();
    if (tid == 0) {
        float tot = red2[0] + red2[1] + red2[2] + red2[3];
        ctrlf[33 + g] = W[set] * tot * (1.0f / (N_PTS * 3.0f * B_VAL));
    }

    __threadfence();
    __shared__ int slast2;
    if (tid == 0) {
        unsigned int t2 = atomicAdd(&ctrl[32], 1u);
        slast2 = (t2 == NGRP - 1);
    }
    __syncthreads();
    if (!slast2) return;

    // ---- phase 3: final assembly (wave 0 of the last merge block) ----
    __threadfence();
    if (tid >= 64) return;
    float L = (tid < NGRP) ? ctrlf[33 + tid] : 0.0f;
    float C = 0.0f;
    if (tid < 48) {                       // 16 sets x 3 components
        const int s = tid / 3, k = tid - s * 3;
        const float a = ctrlf[65 + (s * 2 + 0) * 3 + k] * (1.0f / N_PTS);
        const float b = ctrlf[65 + (s * 2 + 1) * 3 + k] * (1.0f / N_PTS);
        C = sl1(a - b);
    }
    for (int off = 32; off > 0; off >>= 1) {
        L += __shfl_down(L, off, 64);
        C += __shfl_down(C, off, 64);
    }
    if (tid == 0) {
        out[0] = L;
        out[1] = C * (1.0f / (B_VAL * 3.0f));
    }
}

extern "C" void kernel_launch(void* const* d_in, const int* in_sizes, int n_in,
                              void* d_out, int out_size, void* d_ws, size_t ws_size,
                              hipStream_t stream) {
    const float* X = (const float*)d_in[0];
    const float* T = (const float*)d_in[1];
    const float* W = (const float*)d_in[2];
    float* out = (float*)d_out;
    float2* ws = (float2*)d_ws;   // 8 MB partials + 644 B control

    // Counters must start at 0; ws is poisoned by the harness each iteration,
    // so zero just the 256 control bytes (covers ctrl[0..63]).
    hipMemsetAsync((char*)d_ws + CTRL_OFF, 0, 256, stream);
    chamfer_fused<<<dim3(SEGS, N_SETS, 2), BLOCK, 0, stream>>>(X, T, W, ws, out);
}

// Round 3
// 86.772 us; speedup vs baseline: 2.1360x; 2.1360x over previous
//
#include <hip/hip_runtime.h>
#include <math.h>

#define N_PTS 2048
#define N_SETS 16          // B*S = 2*8
#define B_VAL 2.0f
#define BLOCK 256
#define SEGS 16
#define CPS (N_PTS / SEGS)   // 128 candidates per segment
#define QPT 8                // queries per thread (2048 / 256)
#define NGRP (N_SETS * 2)    // 32 (set,dir) groups

// ws layout:
//   [0 .. 8MB)        float2 partials: [(group*SEGS + seg) * 2048 + q]
//   [8MB .. +384B)    float csum[32][3] coordinate sums (written by kernel 1
//                     seg-0 blocks; read by kernel 2 — kernel boundary is the
//                     only sync needed, no fences/counters/memset).
#define CTRL_OFF ((size_t)NGRP * SEGS * N_PTS * sizeof(float2))   // 8 MB

__device__ __forceinline__ float sl1(float d) {
    d = fabsf(d);
    return d < 1.0f ? 0.5f * d * d : d - 0.5f;
}

// grid = (SEGS, N_SETS, 2). Each block: ALL 2048 queries of one (set,dir)
// against a 128-candidate segment. Thread t handles queries t+256*j.
// Per-seg (dist, idx) written contention-free to ws[sd][seg][q].
// SEGS=16 measured-optimal (512 blocks = 1024 waves = exactly 1/SIMD);
// SEGS=32 regressed (R5 +5.6us), packed-fp32 regressed (R4 +2.4us),
// single-kernel threadfence fusion regressed (R6 +100us: device-scope
// fence L2 writeback x512 + 32-block latency tail).
__global__ __launch_bounds__(BLOCK) void chamfer_partial(
    const float* __restrict__ X, const float* __restrict__ T,
    float2* __restrict__ ws, float* __restrict__ out)
{
    const int seg = blockIdx.x;
    const int set = blockIdx.y;
    const int dir = blockIdx.z;
    const int tid = threadIdx.x;
    const int g   = set * 2 + dir;

    if (seg == 0 && set == 0 && dir == 0 && tid == 0)
        out[0] = 0.0f;   // consumed by finalize atomicAdds (stream-ordered)

    const float* psrc = (dir == 0) ? (X + (size_t)set * N_PTS * 3)
                                   : (T + (size_t)set * N_PTS * 3);
    const float* csrc = (dir == 0) ? (T + (size_t)set * N_PTS * 3)
                                   : (X + (size_t)set * N_PTS * 3);

    // Stage this segment's candidates as (x,y,z,|c|^2) float4 in LDS.
    __shared__ float4 cand[CPS];
    if (tid < CPS) {
        const int gi = seg * CPS + tid;
        float cx = csrc[gi * 3 + 0];
        float cy = csrc[gi * 3 + 1];
        float cz = csrc[gi * 3 + 2];
        cand[tid] = make_float4(cx, cy, cz, cx * cx + cy * cy + cz * cz);
    }
    __syncthreads();

    // My 8 query points; precompute -2*coord (|p|^2 dropped: constant
    // shift per query, argmin-invariant).
    float ax[QPT], ay[QPT], az[QPT];
    float best[QPT];
    int   bidx[QPT];
#pragma unroll
    for (int j = 0; j < QPT; ++j) {
        const int q = tid + BLOCK * j;
        ax[j] = -2.0f * psrc[q * 3 + 0];
        ay[j] = -2.0f * psrc[q * 3 + 1];
        az[j] = -2.0f * psrc[q * 3 + 2];
        best[j] = INFINITY;
        bidx[j] = 0;
    }

    // One broadcast LDS read amortized over 8 queries (48 VALU / ds_read).
    // Strict <: first occurrence wins (ascending m) == jnp.argmin tiebreak.
    // Floor: 6 VALU/pair (3 fma + cmp + 2 cndmask) -> ~10 us GPU-wide.
#pragma unroll 4
    for (int m = 0; m < CPS; ++m) {
        float4 c = cand[m];
#pragma unroll
        for (int j = 0; j < QPT; ++j) {
            float d = fmaf(ax[j], c.x, fmaf(ay[j], c.y, fmaf(az[j], c.z, c.w)));
            if (d < best[j]) { best[j] = d; bidx[j] = m; }
        }
    }

    // Contention-free coalesced stores: ws[(g*SEGS+seg)*2048 + q].
    float2* wq = ws + ((size_t)(g * SEGS + seg) << 11);
#pragma unroll
    for (int j = 0; j < QPT; ++j) {
        const int q = tid + BLOCK * j;
        float2 v;
        v.x = best[j];
        v.y = __uint_as_float((unsigned int)(seg * CPS + bidx[j]));
        wq[q] = v;
    }

    // seg-0 blocks also produce this direction's coordinate sums: they already
    // hold every query point in registers. ax = -2x is exact; *(-0.5) is
    // exact, so this matches summing the raw coords bit-for-bit. (Verified
    // correct in the R6 fused kernel, absmax 0.0.)
    if (seg == 0) {
        __shared__ float red[4][3];
        float s0 = 0.f, s1 = 0.f, s2 = 0.f;
#pragma unroll
        for (int j = 0; j < QPT; ++j) { s0 += ax[j]; s1 += ay[j]; s2 += az[j]; }
        for (int off = 32; off > 0; off >>= 1) {
            s0 += __shfl_down(s0, off, 64);
            s1 += __shfl_down(s1, off, 64);
            s2 += __shfl_down(s2, off, 64);
        }
        if ((tid & 63) == 0) {
            red[tid >> 6][0] = s0; red[tid >> 6][1] = s1; red[tid >> 6][2] = s2;
        }
        __syncthreads();   // block-uniform branch (seg is blockIdx.x) — safe
        if (tid == 0) {
            float* cs = (float*)((char*)ws + CTRL_OFF);
#pragma unroll
            for (int k = 0; k < 3; ++k)
                cs[g * 3 + k] =
                    -0.5f * (red[0][k] + red[1][k] + red[2][k] + red[3][k]);
        }
    }
}

// grid = (N_PTS/BLOCK, N_SETS, 2): merge 16 seg-results per query, smooth-L1,
// weighted reduce. Block (0,0,1) additionally assembles the centroid loss
// from kernel-1's csums (one extra wave-wide op, no extra grid chunk).
__global__ __launch_bounds__(BLOCK) void finalize_kernel(
    const float* __restrict__ X, const float* __restrict__ T,
    const float* __restrict__ W, const float2* __restrict__ ws,
    float* __restrict__ out)
{
    const int chunk = blockIdx.x;
    const int set   = blockIdx.y;
    const int dir   = blockIdx.z;
    const int tid   = threadIdx.x;

    const int n = chunk * BLOCK + tid;
    const float* psrc = (dir == 0) ? (X + (size_t)set * N_PTS * 3)
                                   : (T + (size_t)set * N_PTS * 3);
    const float* csrc = (dir == 0) ? (T + (size_t)set * N_PTS * 3)
                                   : (X + (size_t)set * N_PTS * 3);

    // Merge per-seg partials; ascending seg + strict < == lowest-index tiebreak.
    const float2* wq = ws + ((size_t)((set * 2 + dir) * SEGS) << 11);
    float bestd = INFINITY;
    unsigned int idx = 0;
#pragma unroll
    for (int s = 0; s < SEGS; ++s) {
        float2 v = wq[((size_t)s << 11) + n];
        if (v.x < bestd) { bestd = v.x; idx = __float_as_uint(v.y); }
    }

    float s = sl1(psrc[n * 3 + 0] - csrc[idx * 3 + 0])
            + sl1(psrc[n * 3 + 1] - csrc[idx * 3 + 1])
            + sl1(psrc[n * 3 + 2] - csrc[idx * 3 + 2]);

    __shared__ float wpart[4];
    for (int off = 32; off > 0; off >>= 1)
        s += __shfl_down(s, off, 64);
    if ((tid & 63) == 0) wpart[tid >> 6] = s;
    __syncthreads();
    if (tid == 0) {
        float tot = wpart[0] + wpart[1] + wpart[2] + wpart[3];
        atomicAdd(&out[0], W[set] * tot * (1.0f / (N_PTS * 3.0f * B_VAL)));
    }

    // ---- centroid assembly: one designated block, wave 0 only ----
    if (chunk == 0 && set == 0 && dir == 1 && tid < 64) {
        const float* cs = (const float*)((const char*)ws + CTRL_OFF);
        float C = 0.0f;
        if (tid < 48) {                   // 16 sets x 3 components
            const int st = tid / 3, k = tid - st * 3;
            const float a = cs[(st * 2 + 0) * 3 + k] * (1.0f / N_PTS);
            const float b = cs[(st * 2 + 1) * 3 + k] * (1.0f / N_PTS);
            C = sl1(a - b);
        }
        for (int off = 32; off > 0; off >>= 1)
            C += __shfl_down(C, off, 64);
        if (tid == 0)
            out[1] = C * (1.0f / (B_VAL * 3.0f));
    }
}

extern "C" void kernel_launch(void* const* d_in, const int* in_sizes, int n_in,
                              void* d_out, int out_size, void* d_ws, size_t ws_size,
                              hipStream_t stream) {
    const float* X = (const float*)d_in[0];
    const float* T = (const float*)d_in[1];
    const float* W = (const float*)d_in[2];
    float* out = (float*)d_out;
    float2* ws = (float2*)d_ws;   // 8 MB partials + 384 B csums

    chamfer_partial<<<dim3(SEGS, N_SETS, 2), BLOCK, 0, stream>>>(X, T, ws, out);
    finalize_kernel<<<dim3(N_PTS / BLOCK, N_SETS, 2), BLOCK, 0, stream>>>(X, T, W, ws, out);
}